// Round 2
// baseline (302.875 us; speedup 1.0000x reference)
//
#include <hip/hip_runtime.h>
#include <hip/hip_bf16.h>
#include <math.h>

#define B_SZ 16
#define T_SZ 128
#define N_P 12
#define D_SZ 1024
#define D2_SZ 2048
#define BT 2048          // B*T tokens
#define KDIM 2048        // inner dim of projections (2D)
#define EALL 8192        // 4*1024 (tb,pb,ta,pa) + 2*2048 (gb,ga)
#define EPROJ 4096       // tb|pb|ta|pa row width

typedef __attribute__((ext_vector_type(8))) short short8;    // 8 bf16 = 4 VGPRs
typedef __attribute__((ext_vector_type(4))) float floatx4;   // MFMA C/D

__device__ inline void gload_lds16(const void* g, void* l) {
  __builtin_amdgcn_global_load_lds(
      (const __attribute__((address_space(1))) void*)g,
      (__attribute__((address_space(3))) void*)l, 16, 0, 0);
}

__device__ inline unsigned short f2bf(float x) {
  union { __hip_bfloat16 h; unsigned short u; } cv;
  cv.h = __float2bfloat16(x);
  return cv.u;
}
__device__ inline float bf2f(unsigned short u) {
  return __uint_as_float(((unsigned)u) << 16);
}

// ---------------------------------------------------------------------------
// Kernel A: build n = [g ; max] per token, bf16 out. One block per token.
// ---------------------------------------------------------------------------
__global__ __launch_bounds__(256) void build_n_kernel(
    const float* __restrict__ feat, const float* __restrict__ Wq,
    unsigned short* __restrict__ Nbf) {
  const int t = blockIdx.x;
  const int tid = threadIdx.x;
  const float4* fb4 = (const float4*)(feat + (size_t)t * N_P * D_SZ);
  const float4* wq4 = (const float4*)Wq;

  float4 q = {0.f, 0.f, 0.f, 0.f};
#pragma unroll
  for (int m = 0; m < N_P; ++m) {
    const float4 v = wq4[m * 256 + tid];
    q.x += v.x; q.y += v.y; q.z += v.z; q.w += v.w;
  }

  float4 fv[N_P];
  float part[N_P];
#pragma unroll
  for (int n = 0; n < N_P; ++n) {
    const float4 f = fb4[n * 256 + tid];
    fv[n] = f;
    part[n] = f.x * q.x + f.y * q.y + f.z * q.z + f.w * q.w;
  }

  __shared__ float wred[N_P * 4];
  const int lane = tid & 63;
  const int wave = tid >> 6;
#pragma unroll
  for (int n = 0; n < N_P; ++n) {
    float v = part[n];
#pragma unroll
    for (int off = 32; off; off >>= 1) v += __shfl_down(v, off);
    if (lane == 0) wred[n * 4 + wave] = v;
  }
  __syncthreads();

  float w[N_P];
#pragma unroll
  for (int n = 0; n < N_P; ++n)
    w[n] = wred[n * 4 + 0] + wred[n * 4 + 1] + wred[n * 4 + 2] + wred[n * 4 + 3];

  float4 g = {0.f, 0.f, 0.f, 0.f};
  float4 fm = {-INFINITY, -INFINITY, -INFINITY, -INFINITY};
#pragma unroll
  for (int n = 0; n < N_P; ++n) {
    const float4 f = fv[n];
    g.x += w[n] * f.x; g.y += w[n] * f.y; g.z += w[n] * f.z; g.w += w[n] * f.w;
    fm.x = fmaxf(fm.x, f.x); fm.y = fmaxf(fm.y, f.y);
    fm.z = fmaxf(fm.z, f.z); fm.w = fmaxf(fm.w, f.w);
  }
  ushort4 og, of;
  og.x = f2bf(g.x); og.y = f2bf(g.y); og.z = f2bf(g.z); og.w = f2bf(g.w);
  of.x = f2bf(fm.x); of.y = f2bf(fm.y); of.z = f2bf(fm.z); of.w = f2bf(fm.w);
  *(ushort4*)&Nbf[(size_t)t * D2_SZ + tid * 4] = og;
  *(ushort4*)&Nbf[(size_t)t * D2_SZ + D_SZ + tid * 4] = of;
}

// ---------------------------------------------------------------------------
// Weight conversion. grid (2048, 6). r<4: 1 float4/thread; r>=4: 2 (g mats).
// Wb row order: [tb | pb | ta | pa | gb | ga]
// ---------------------------------------------------------------------------
__global__ __launch_bounds__(256) void cvt_all(
    const float* __restrict__ Wtb, const float* __restrict__ Wpb,
    const float* __restrict__ Wta, const float* __restrict__ Wpa,
    const float* __restrict__ Wgb, const float* __restrict__ Wga,
    unsigned short* __restrict__ Wb) {
  const int r = blockIdx.y;
  const int i = blockIdx.x * 256 + threadIdx.x;   // < 524288
  const float* src;
  size_t off;
  switch (r) {
    case 0: src = Wtb; off = 0; break;
    case 1: src = Wpb; off = (size_t)1024 * KDIM; break;
    case 2: src = Wta; off = (size_t)2048 * KDIM; break;
    case 3: src = Wpa; off = (size_t)3072 * KDIM; break;
    case 4: src = Wgb; off = (size_t)4096 * KDIM; break;
    default: src = Wga; off = (size_t)6144 * KDIM; break;
  }
  {
    const float4 v = ((const float4*)src)[i];
    ushort4 o;
    o.x = f2bf(v.x); o.y = f2bf(v.y); o.z = f2bf(v.z); o.w = f2bf(v.w);
    ((ushort4*)(Wb + off))[i] = o;
  }
  if (r >= 4) {
    const int i2 = i + 524288;
    const float4 v = ((const float4*)src)[i2];
    ushort4 o;
    o.x = f2bf(v.x); o.y = f2bf(v.y); o.z = f2bf(v.z); o.w = f2bf(v.w);
    ((ushort4*)(Wb + off))[i2] = o;
  }
}

// ---------------------------------------------------------------------------
// Kernel B: fused projection GEMM, bf16 MFMA.
// 256x256 tile, BK=32, 8 waves (2M x 4N), ring-of-4 LDS pipeline (prefetch
// distance 3), counted vmcnt(8) (T4), bijective XCD swizzle (T1), LDS XOR
// swizzle (T2), and NOW: 2-phase interleave per K-step (T3) with setprio
// around each 16-MFMA cluster (T5). 8 MFMA per barrier = m201 density.
//
// Phase A: ds_read A[0..3]+B[0..3] (8 reads) | stage 2 gloads (slot t+3)
//          | bar | lgkm0 | 16 MFMA (A[0..3] x B) | bar
// Phase B: ds_read A[4..7] (4 reads)         | stage 2 gloads
//          | vmcnt(8) | bar | lgkm0 | 16 MFMA (A[4..7] x B) | bar
//
// Ring safety (unchanged from verified round-1 schedule):
//  - step t reads slot t&3, staged at step t-3; landed per step t-1's
//    vmcnt(8)+final-barrier (all but the newest 2 stage batches landed).
//  - step t stages slot (t+3)&3, which step t-1 finished reading before
//    its final barrier (lgkm0 precedes it), and every wave passed that
//    barrier before any stage of step t issues.
// ---------------------------------------------------------------------------
__global__ __launch_bounds__(512, 2) void gemm_fused(
    const unsigned short* __restrict__ X,
    const unsigned short* __restrict__ Wb,
    unsigned short* __restrict__ Cproj,
    unsigned short* __restrict__ Gbt,
    unsigned short* __restrict__ Gat) {
  __shared__ __align__(16) unsigned short lds[4 * 16384];  // 128 KiB ring
  const int tid = threadIdx.x;
  const int lane = tid & 63;
  const int w = tid >> 6;           // 0..7
  const int quad = lane >> 4;
  const int l15 = lane & 15;
  const int wm = (w >> 2) * 128;    // wave row (2 waves in M)
  const int wn = (w & 3) * 64;      // wave col (4 waves in N)

  // XCD-aware bijective swizzle: 256 blocks, 8 XCDs -> each XCD gets
  // be in {4x..4x+3} x all 8 m-tiles => its 4 B-panels (4 MB) stay L2-hot.
  const int bid = blockIdx.x;
  const int swz = (bid & 7) * 32 + (bid >> 3);
  const int m0 = (swz & 7) * 256;   // token tile
  const int be = swz >> 3;          // 0..31 E-tile
  const int e0 = be * 256;

  floatx4 acc[8][4];
#pragma unroll
  for (int mt = 0; mt < 8; ++mt)
#pragma unroll
    for (int nt = 0; nt < 4; ++nt) {
      floatx4 z = {0.f, 0.f, 0.f, 0.f};
      acc[mt][nt] = z;
    }

  // staging: per K-step 32 KB (A 256x32 + B 256x32 bf16) = 512 thr x 64 B
  // -> 4 global_load_lds of 16 B per thread (one vmcnt batch of 4).
  const unsigned short* srcA[2];
  const unsigned short* srcB[2];
  int dstOff[2];
#pragma unroll
  for (int c = 0; c < 2; ++c) {
    const int s = tid + c * 512;              // slot 0..1023
    const int row = s >> 2;                   // 0..255
    const int ccg = (s & 3) ^ ((row >> 1) & 3);  // swizzled source chunk
    srcA[c] = X + (size_t)(m0 + row) * KDIM + ccg * 8;
    srcB[c] = Wb + (size_t)(e0 + row) * KDIM + ccg * 8;
    dstOff[c] = s * 8;                        // linear LDS (ushorts)
  }

  // loop-invariant swizzled fragment offsets (ushorts within ring slot)
  int aofs[8], bofs[4];
#pragma unroll
  for (int mt = 0; mt < 8; ++mt) {
    const int row = wm + mt * 16 + l15;
    aofs[mt] = row * 32 + ((quad ^ ((row >> 1) & 3)) * 8);
  }
#pragma unroll
  for (int nt = 0; nt < 4; ++nt) {
    const int row = wn + nt * 16 + l15;
    bofs[nt] = 8192 + row * 32 + ((quad ^ ((row >> 1) & 3)) * 8);
  }

  auto STAGE_A = [&](int t) {   // both A half-loads for ring slot t&3
    const int rb_ = (t & 3) * 16384;
    const int k0_ = t * 32;
#pragma unroll
    for (int c = 0; c < 2; ++c)
      gload_lds16(srcA[c] + k0_, &lds[rb_ + dstOff[c]]);
  };
  auto STAGE_B = [&](int t) {   // both B half-loads for ring slot t&3
    const int rb_ = (t & 3) * 16384;
    const int k0_ = t * 32;
#pragma unroll
    for (int c = 0; c < 2; ++c)
      gload_lds16(srcB[c] + k0_, &lds[rb_ + 8192 + dstOff[c]]);
  };

  // prologue: fill 3 ring slots; need slot0 landed -> vmcnt(8) (2 batches
  // may stay in flight), then barrier for the workgroup-wide guarantee.
  STAGE_A(0); STAGE_B(0);
  STAGE_A(1); STAGE_B(1);
  STAGE_A(2); STAGE_B(2);
  __builtin_amdgcn_sched_barrier(0);
  asm volatile("s_waitcnt vmcnt(8)" ::: "memory");
  __builtin_amdgcn_sched_barrier(0);
  __builtin_amdgcn_s_barrier();
  __builtin_amdgcn_sched_barrier(0);

  for (int t = 0; t < 64; ++t) {            // KDIM/32 = 64 steps
    const int rb = (t & 3) * 16384;
    // ---------------- Phase A ----------------
    short8 a[4], b[4];
#pragma unroll
    for (int mt = 0; mt < 4; ++mt) a[mt] = *(const short8*)&lds[rb + aofs[mt]];
#pragma unroll
    for (int nt = 0; nt < 4; ++nt) b[nt] = *(const short8*)&lds[rb + bofs[nt]];
    if (t + 3 < 64) STAGE_A(t + 3);
    __builtin_amdgcn_sched_barrier(0);
    __builtin_amdgcn_s_barrier();
    asm volatile("s_waitcnt lgkmcnt(0)" ::: "memory");
    __builtin_amdgcn_sched_barrier(0);
    __builtin_amdgcn_s_setprio(1);
#pragma unroll
    for (int mt = 0; mt < 4; ++mt)
#pragma unroll
      for (int nt = 0; nt < 4; ++nt)
        acc[mt][nt] = __builtin_amdgcn_mfma_f32_16x16x32_bf16(
            a[mt], b[nt], acc[mt][nt], 0, 0, 0);
    __builtin_amdgcn_s_setprio(0);
    __builtin_amdgcn_sched_barrier(0);
    __builtin_amdgcn_s_barrier();
    __builtin_amdgcn_sched_barrier(0);
    // ---------------- Phase B ----------------
    short8 a2[4];
#pragma unroll
    for (int mt = 0; mt < 4; ++mt)
      a2[mt] = *(const short8*)&lds[rb + aofs[4 + mt]];
    if (t + 3 < 64) STAGE_B(t + 3);
    __builtin_amdgcn_sched_barrier(0);
    // counted vmcnt: guarantee step t+1's batch landed; epilogue drains.
    if (t + 3 < 64) {
      asm volatile("s_waitcnt vmcnt(8)" ::: "memory");
    } else if (t + 2 < 64) {
      asm volatile("s_waitcnt vmcnt(4)" ::: "memory");
    } else if (t + 1 < 64) {
      asm volatile("s_waitcnt vmcnt(0)" ::: "memory");
    }
    __builtin_amdgcn_sched_barrier(0);
    __builtin_amdgcn_s_barrier();
    asm volatile("s_waitcnt lgkmcnt(0)" ::: "memory");
    __builtin_amdgcn_sched_barrier(0);
    __builtin_amdgcn_s_setprio(1);
#pragma unroll
    for (int mt = 0; mt < 4; ++mt)
#pragma unroll
      for (int nt = 0; nt < 4; ++nt)
        acc[4 + mt][nt] = __builtin_amdgcn_mfma_f32_16x16x32_bf16(
            a2[mt], b[nt], acc[4 + mt][nt], 0, 0, 0);
    __builtin_amdgcn_s_setprio(0);
    __builtin_amdgcn_sched_barrier(0);
    __builtin_amdgcn_s_barrier();
    __builtin_amdgcn_sched_barrier(0);
  }

  if (be < 16) {
#pragma unroll
    for (int mt = 0; mt < 8; ++mt)
#pragma unroll
      for (int nt = 0; nt < 4; ++nt) {
        const int col = e0 + wn + nt * 16 + l15;
#pragma unroll
        for (int r = 0; r < 4; ++r) {
          const int rowg = m0 + wm + mt * 16 + quad * 4 + r;
          Cproj[(size_t)rowg * EPROJ + col] = f2bf(acc[mt][nt][r]);
        }
      }
  } else {
    unsigned short* Gt = (be < 24) ? Gbt : Gat;
    const int fb = e0 - ((be < 24) ? 4096 : 6144);
#pragma unroll
    for (int mt = 0; mt < 8; ++mt)
#pragma unroll
      for (int nt = 0; nt < 4; ++nt) {
        const int f = fb + wn + nt * 16 + l15;
        const int tok0 = m0 + wm + mt * 16 + quad * 4;
        ushort4 o;
        o.x = f2bf(acc[mt][nt][0]); o.y = f2bf(acc[mt][nt][1]);
        o.z = f2bf(acc[mt][nt][2]); o.w = f2bf(acc[mt][nt][3]);
        *(ushort4*)&Gt[(size_t)f * BT + tok0] = o;
      }
  }
}

// ---------------------------------------------------------------------------
// Kernel C: score partials via MFMA. grid (16 batches, 2 branches, 4 K-chunks).
// Spart[(br*16+b)*4+kc][i][j] (fp32, unmasked, unscaled).
// ---------------------------------------------------------------------------
__global__ __launch_bounds__(256) void score_kernel(
    const unsigned short* __restrict__ Cproj, float* __restrict__ Spart) {
  const int b = blockIdx.x;
  const int br = blockIdx.y;
  const int kc = blockIdx.z;
  const int aoff = br ? 2048 : 0;   // ta : tb
  const int boff = aoff + 1024;     // pa : pb

  __shared__ __align__(16) unsigned short As[128 * 32];
  __shared__ __align__(16) unsigned short Bs[128 * 32];
  const int tid = threadIdx.x;
  const int lane = tid & 63;
  const int w = tid >> 6;
  const int wm = (w >> 1) * 64;
  const int wn = (w & 1) * 64;
  const int quad = lane >> 4;
  const int l15 = lane & 15;
  const int t0 = b * T_SZ;

  floatx4 acc[4][4];
#pragma unroll
  for (int mt = 0; mt < 4; ++mt)
#pragma unroll
    for (int nt = 0; nt < 4; ++nt) {
      floatx4 z = {0.f, 0.f, 0.f, 0.f};
      acc[mt][nt] = z;
    }

  const unsigned short* gA[2];
  const unsigned short* gB[2];
  unsigned short* lA[2];
  unsigned short* lB[2];
#pragma unroll
  for (int c = 0; c < 2; ++c) {
    const int s = w * 64 + lane + c * 256;
    const int row = s >> 2;
    const int ccg = (s & 3) ^ ((row >> 1) & 3);
    gA[c] = Cproj + (size_t)(t0 + row) * EPROJ + aoff + ccg * 8;
    gB[c] = Cproj + (size_t)(t0 + row) * EPROJ + boff + ccg * 8;
    lA[c] = &As[(size_t)s * 8];
    lB[c] = &Bs[(size_t)s * 8];
  }

  int aofs[4], bofs[4];
#pragma unroll
  for (int mt = 0; mt < 4; ++mt) {
    const int row = wm + mt * 16 + l15;
    aofs[mt] = row * 32 + ((quad ^ ((row >> 1) & 3)) * 8);
  }
#pragma unroll
  for (int nt = 0; nt < 4; ++nt) {
    const int row = wn + nt * 16 + l15;
    bofs[nt] = row * 32 + ((quad ^ ((row >> 1) & 3)) * 8);
  }

  const int kbeg = kc * 256;
  for (int k0 = kbeg; k0 < kbeg + 256; k0 += 32) {
#pragma unroll
    for (int c = 0; c < 2; ++c) {
      gload_lds16(gA[c] + k0, lA[c]);
      gload_lds16(gB[c] + k0, lB[c]);
    }
    __syncthreads();
    short8 a[4], bb[4];
#pragma unroll
    for (int mt = 0; mt < 4; ++mt) a[mt] = *(const short8*)&As[aofs[mt]];
#pragma unroll
    for (int nt = 0; nt < 4; ++nt) bb[nt] = *(const short8*)&Bs[bofs[nt]];
#pragma unroll
    for (int mt = 0; mt < 4; ++mt)
#pragma unroll
      for (int nt = 0; nt < 4; ++nt)
        acc[mt][nt] = __builtin_amdgcn_mfma_f32_16x16x32_bf16(
            a[mt], bb[nt], acc[mt][nt], 0, 0, 0);
    __syncthreads();
  }

  float* Sp = Spart + ((size_t)(br * B_SZ + b) * 4 + kc) * T_SZ * T_SZ;
#pragma unroll
  for (int mt = 0; mt < 4; ++mt)
#pragma unroll
    for (int nt = 0; nt < 4; ++nt) {
      const int j = wn + nt * 16 + l15;
#pragma unroll
      for (int r = 0; r < 4; ++r) {
        const int i = wm + mt * 16 + quad * 4 + r;
        Sp[(size_t)i * T_SZ + j] = acc[mt][nt][r];
      }
    }
}

// ---------------------------------------------------------------------------
// Combine: Sbf = f2bf(mask * scale * sum_kc Spart). 512 blocks x 256 thr,
// one j4-group (4 cols) per thread.
// ---------------------------------------------------------------------------
__global__ __launch_bounds__(256) void score_combine(
    const float* __restrict__ Spart, unsigned short* __restrict__ Sbf) {
  const float scale = 0.022097086912079608f;  // 1/sqrt(2*1024)
  const int gid = blockIdx.x * 256 + threadIdx.x;   // < 131072
  const int j4 = gid & 31;
  const int i = (gid >> 5) & 127;
  const int bb = (gid >> 12) & 15;
  const int br = gid >> 16;
  const size_t base = ((size_t)(br * B_SZ + bb) * 4) * T_SZ * T_SZ +
                      (size_t)i * T_SZ + j4 * 4;
  float4 s = {0.f, 0.f, 0.f, 0.f};
#pragma unroll
  for (int kc = 0; kc < 4; ++kc) {
    const float4 v = *(const float4*)&Spart[base + (size_t)kc * T_SZ * T_SZ];
    s.x += v.x; s.y += v.y; s.z += v.z; s.w += v.w;
  }
  const int j0 = j4 * 4;
  ushort4 o;
  o.x = f2bf((br ? (j0 + 0 > i) : (j0 + 0 < i)) ? s.x * scale : 0.f);
  o.y = f2bf((br ? (j0 + 1 > i) : (j0 + 1 < i)) ? s.y * scale : 0.f);
  o.z = f2bf((br ? (j0 + 2 > i) : (j0 + 2 < i)) ? s.z * scale : 0.f);
  o.w = f2bf((br ? (j0 + 3 > i) : (j0 + 3 < i)) ? s.w * scale : 0.f);
  *(ushort4*)&Sbf[((size_t)(br * B_SZ + bb)) * T_SZ * T_SZ +
                  (size_t)i * T_SZ + j0] = o;
}

// ---------------------------------------------------------------------------
// Kernel D: PV via MFMA, no LDS.
// ---------------------------------------------------------------------------
__global__ __launch_bounds__(256) void pv_mfma(
    const unsigned short* __restrict__ Nbf,
    const unsigned short* __restrict__ Sbf,
    const unsigned short* __restrict__ Gbt,
    const unsigned short* __restrict__ Gat,
    float* __restrict__ out) {
  const int ft = blockIdx.x;
  const int b = blockIdx.y;
  const int f0 = ft * 128;
  const int t0 = b * T_SZ;
  const int tid = threadIdx.x;
  const int lane = tid & 63;
  const int w = tid >> 6;
  const int wm = (w >> 1) * 64;   // token dim
  const int wn = (w & 1) * 64;    // f dim
  const int quad = lane >> 4;
  const int l15 = lane & 15;

  const unsigned short* Sb = Sbf + ((size_t)0 * B_SZ + b) * T_SZ * T_SZ;
  const unsigned short* Sa = Sbf + ((size_t)1 * B_SZ + b) * T_SZ * T_SZ;

  floatx4 acc[4][4];
#pragma unroll
  for (int mt = 0; mt < 4; ++mt)
#pragma unroll
    for (int nt = 0; nt < 4; ++nt) {
      floatx4 z = {0.f, 0.f, 0.f, 0.f};
      acc[mt][nt] = z;
    }

#pragma unroll
  for (int k0 = 0; k0 < T_SZ; k0 += 32) {
    short8 ab[4], aa[4], bb[4], ba[4];
#pragma unroll
    for (int mt = 0; mt < 4; ++mt) {
      const int i = wm + mt * 16 + l15;
      ab[mt] = *(const short8*)&Sb[(size_t)i * T_SZ + k0 + quad * 8];
      aa[mt] = *(const short8*)&Sa[(size_t)i * T_SZ + k0 + quad * 8];
    }
#pragma unroll
    for (int nt = 0; nt < 4; ++nt) {
      const int f = f0 + wn + nt * 16 + l15;
      bb[nt] = *(const short8*)&Gbt[(size_t)f * BT + t0 + k0 + quad * 8];
      ba[nt] = *(const short8*)&Gat[(size_t)f * BT + t0 + k0 + quad * 8];
    }
#pragma unroll
    for (int mt = 0; mt < 4; ++mt)
#pragma unroll
      for (int nt = 0; nt < 4; ++nt) {
        acc[mt][nt] = __builtin_amdgcn_mfma_f32_16x16x32_bf16(
            ab[mt], bb[nt], acc[mt][nt], 0, 0, 0);
        acc[mt][nt] = __builtin_amdgcn_mfma_f32_16x16x32_bf16(
            aa[mt], ba[nt], acc[mt][nt], 0, 0, 0);
      }
  }

#pragma unroll
  for (int mt = 0; mt < 4; ++mt)
#pragma unroll
    for (int nt = 0; nt < 4; ++nt) {
      const int f = f0 + wn + nt * 16 + l15;
#pragma unroll
      for (int r = 0; r < 4; ++r) {
        const int tok = t0 + wm + mt * 16 + quad * 4 + r;
        out[(size_t)tok * D2_SZ + f] =
            acc[mt][nt][r] + bf2f(Nbf[(size_t)tok * D2_SZ + f]);
      }
    }
}

// ---------------------------------------------------------------------------
extern "C" void kernel_launch(void* const* d_in, const int* in_sizes, int n_in,
                              void* d_out, int out_size, void* d_ws, size_t ws_size,
                              hipStream_t stream) {
  const float* feat = (const float*)d_in[0];
  const float* Wq  = (const float*)d_in[1];
  const float* Wtb = (const float*)d_in[2];
  const float* Wpb = (const float*)d_in[3];
  const float* Wgb = (const float*)d_in[4];  // dict order: gb before ta
  const float* Wta = (const float*)d_in[5];
  const float* Wpa = (const float*)d_in[6];
  const float* Wga = (const float*)d_in[7];
  float* out = (float*)d_out;

  unsigned short* ws = (unsigned short*)d_ws;
  unsigned short* Nbf   = ws;                                 // [2048][2048] bf16
  unsigned short* Wb    = Nbf + (size_t)BT * D2_SZ;           // [8192][2048] bf16
  unsigned short* Cproj = Wb + (size_t)EALL * KDIM;           // [2048][4096] bf16
  unsigned short* Gbt   = Cproj + (size_t)BT * EPROJ;         // [2048][2048] bf16
  unsigned short* Gat   = Gbt + (size_t)D2_SZ * BT;           // [2048][2048] bf16
  unsigned short* Sbf   = Gat + (size_t)D2_SZ * BT;           // [2][16][128][128] bf16
  float* Spart = (float*)(Sbf + (size_t)2 * B_SZ * T_SZ * T_SZ); // [2][16][4][128][128] f32

  build_n_kernel<<<BT, 256, 0, stream>>>(feat, Wq, Nbf);
  cvt_all<<<dim3(2048, 6), 256, 0, stream>>>(Wtb, Wpb, Wta, Wpa, Wgb, Wga, Wb);
  gemm_fused<<<dim3(256), 512, 0, stream>>>(Nbf, Wb, Cproj, Gbt, Gat);
  score_kernel<<<dim3(B_SZ, 2, 4), 256, 0, stream>>>(Cproj, Spart);
  score_combine<<<512, 256, 0, stream>>>(Spart, Sbf);
  pv_mfma<<<dim3(D2_SZ / 128, B_SZ), 256, 0, stream>>>(Nbf, Sbf, Gbt, Gat, out);
}

// Round 3
// 300.780 us; speedup vs baseline: 1.0070x; 1.0070x over previous
//
#include <hip/hip_runtime.h>
#include <hip/hip_bf16.h>
#include <math.h>

#define B_SZ 16
#define T_SZ 128
#define N_P 12
#define D_SZ 1024
#define D2_SZ 2048
#define BT 2048          // B*T tokens
#define KDIM 2048        // inner dim of projections (2D)
#define EALL 8192        // 4*1024 (tb,pb,ta,pa) + 2*2048 (gb,ga)
#define EPROJ 4096       // tb|pb|ta|pa row width

typedef __attribute__((ext_vector_type(8))) short short8;    // 8 bf16 = 4 VGPRs
typedef __attribute__((ext_vector_type(4))) float floatx4;   // MFMA C/D

__device__ inline void gload_lds16(const void* g, void* l) {
  __builtin_amdgcn_global_load_lds(
      (const __attribute__((address_space(1))) void*)g,
      (__attribute__((address_space(3))) void*)l, 16, 0, 0);
}

__device__ inline unsigned short f2bf(float x) {
  union { __hip_bfloat16 h; unsigned short u; } cv;
  cv.h = __float2bfloat16(x);
  return cv.u;
}
__device__ inline float bf2f(unsigned short u) {
  return __uint_as_float(((unsigned)u) << 16);
}

// ---------------------------------------------------------------------------
// Kernel A: build n = [g ; max] per token, bf16 out. One block per token.
// ---------------------------------------------------------------------------
__global__ __launch_bounds__(256) void build_n_kernel(
    const float* __restrict__ feat, const float* __restrict__ Wq,
    unsigned short* __restrict__ Nbf) {
  const int t = blockIdx.x;
  const int tid = threadIdx.x;
  const float4* fb4 = (const float4*)(feat + (size_t)t * N_P * D_SZ);
  const float4* wq4 = (const float4*)Wq;

  float4 q = {0.f, 0.f, 0.f, 0.f};
#pragma unroll
  for (int m = 0; m < N_P; ++m) {
    const float4 v = wq4[m * 256 + tid];
    q.x += v.x; q.y += v.y; q.z += v.z; q.w += v.w;
  }

  float4 fv[N_P];
  float part[N_P];
#pragma unroll
  for (int n = 0; n < N_P; ++n) {
    const float4 f = fb4[n * 256 + tid];
    fv[n] = f;
    part[n] = f.x * q.x + f.y * q.y + f.z * q.z + f.w * q.w;
  }

  __shared__ float wred[N_P * 4];
  const int lane = tid & 63;
  const int wave = tid >> 6;
#pragma unroll
  for (int n = 0; n < N_P; ++n) {
    float v = part[n];
#pragma unroll
    for (int off = 32; off; off >>= 1) v += __shfl_down(v, off);
    if (lane == 0) wred[n * 4 + wave] = v;
  }
  __syncthreads();

  float w[N_P];
#pragma unroll
  for (int n = 0; n < N_P; ++n)
    w[n] = wred[n * 4 + 0] + wred[n * 4 + 1] + wred[n * 4 + 2] + wred[n * 4 + 3];

  float4 g = {0.f, 0.f, 0.f, 0.f};
  float4 fm = {-INFINITY, -INFINITY, -INFINITY, -INFINITY};
#pragma unroll
  for (int n = 0; n < N_P; ++n) {
    const float4 f = fv[n];
    g.x += w[n] * f.x; g.y += w[n] * f.y; g.z += w[n] * f.z; g.w += w[n] * f.w;
    fm.x = fmaxf(fm.x, f.x); fm.y = fmaxf(fm.y, f.y);
    fm.z = fmaxf(fm.z, f.z); fm.w = fmaxf(fm.w, f.w);
  }
  ushort4 og, of;
  og.x = f2bf(g.x); og.y = f2bf(g.y); og.z = f2bf(g.z); og.w = f2bf(g.w);
  of.x = f2bf(fm.x); of.y = f2bf(fm.y); of.z = f2bf(fm.z); of.w = f2bf(fm.w);
  *(ushort4*)&Nbf[(size_t)t * D2_SZ + tid * 4] = og;
  *(ushort4*)&Nbf[(size_t)t * D2_SZ + D_SZ + tid * 4] = of;
}

// ---------------------------------------------------------------------------
// Weight conversion. grid (2048, 6). r<4: 1 float4/thread; r>=4: 2 (g mats).
// Wb row order: [tb | pb | ta | pa | gb | ga]
// ---------------------------------------------------------------------------
__global__ __launch_bounds__(256) void cvt_all(
    const float* __restrict__ Wtb, const float* __restrict__ Wpb,
    const float* __restrict__ Wta, const float* __restrict__ Wpa,
    const float* __restrict__ Wgb, const float* __restrict__ Wga,
    unsigned short* __restrict__ Wb) {
  const int r = blockIdx.y;
  const int i = blockIdx.x * 256 + threadIdx.x;   // < 524288
  const float* src;
  size_t off;
  switch (r) {
    case 0: src = Wtb; off = 0; break;
    case 1: src = Wpb; off = (size_t)1024 * KDIM; break;
    case 2: src = Wta; off = (size_t)2048 * KDIM; break;
    case 3: src = Wpa; off = (size_t)3072 * KDIM; break;
    case 4: src = Wgb; off = (size_t)4096 * KDIM; break;
    default: src = Wga; off = (size_t)6144 * KDIM; break;
  }
  {
    const float4 v = ((const float4*)src)[i];
    ushort4 o;
    o.x = f2bf(v.x); o.y = f2bf(v.y); o.z = f2bf(v.z); o.w = f2bf(v.w);
    ((ushort4*)(Wb + off))[i] = o;
  }
  if (r >= 4) {
    const int i2 = i + 524288;
    const float4 v = ((const float4*)src)[i2];
    ushort4 o;
    o.x = f2bf(v.x); o.y = f2bf(v.y); o.z = f2bf(v.z); o.w = f2bf(v.w);
    ((ushort4*)(Wb + off))[i2] = o;
  }
}

// ---------------------------------------------------------------------------
// Kernel B: fused projection GEMM, bf16 MFMA.
// 256x256 tile, BK=32, 8 waves (2M x 4N), ring-of-4 LDS, prefetch dist 3,
// counted vmcnt (T4), XCD swizzle (T1), LDS XOR swizzle (T2), setprio (T5),
// and PIPELINED 2-phase interleave (T3): ds_reads are issued one phase
// AHEAD of the MFMA that consumes them; lgkmcnt(N) waits only for the
// older reads. 2 barriers/step, 1 vmcnt/step.
//
// Step t (steady state):
//  P1: ds_read a47 <- slot t (4)      | STAGE_A(t+3)
//  P3: vmcnt(6)  -> slot t+1 landed (in-flight: t+1:4,t+2:4,t+3A:2 = 10)
//  P4: s_barrier -> landing is workgroup-wide
//  P5: lgkm(4)   -> a03,b (read last step) ready; a47 still in flight
//  P6: 16 MFMA a03 x b
//  P7: ds_read a03,b <- slot t+1 (8)  | STAGE_B(t+3)
//  P9: lgkm(8)   -> a47 ready (8 new reads pend); completes BEFORE barrier
//                  so slot-t reads are all done pre-barrier (WAR safety for
//                  next step's STAGE_A writing slot (t+4)&3 == t&3... i.e.
//                  slot t-1 pattern holds each step)
//  P10: s_barrier
//  P11: 16 MFMA a47 x b
// Register double-buffer for a03/b via parity-unrolled loop (static idx).
// ---------------------------------------------------------------------------
__global__ __launch_bounds__(512, 2) void gemm_fused(
    const unsigned short* __restrict__ X,
    const unsigned short* __restrict__ Wb,
    unsigned short* __restrict__ Cproj,
    unsigned short* __restrict__ Gbt,
    unsigned short* __restrict__ Gat) {
  __shared__ __align__(16) unsigned short lds[4 * 16384];  // 128 KiB ring
  const int tid = threadIdx.x;
  const int lane = tid & 63;
  const int w = tid >> 6;           // 0..7
  const int quad = lane >> 4;
  const int l15 = lane & 15;
  const int wm = (w >> 2) * 128;    // wave row (2 waves in M)
  const int wn = (w & 3) * 64;      // wave col (4 waves in N)

  // XCD-aware bijective swizzle: 256 blocks, 8 XCDs.
  const int bid = blockIdx.x;
  const int swz = (bid & 7) * 32 + (bid >> 3);
  const int m0 = (swz & 7) * 256;   // token tile
  const int be = swz >> 3;          // 0..31 E-tile
  const int e0 = be * 256;

  floatx4 acc[8][4];
#pragma unroll
  for (int mt = 0; mt < 8; ++mt)
#pragma unroll
    for (int nt = 0; nt < 4; ++nt) {
      floatx4 z = {0.f, 0.f, 0.f, 0.f};
      acc[mt][nt] = z;
    }

  const unsigned short* srcA[2];
  const unsigned short* srcB[2];
  int dstOff[2];
#pragma unroll
  for (int c = 0; c < 2; ++c) {
    const int s = tid + c * 512;              // slot 0..1023
    const int row = s >> 2;                   // 0..255
    const int ccg = (s & 3) ^ ((row >> 1) & 3);  // swizzled source chunk
    srcA[c] = X + (size_t)(m0 + row) * KDIM + ccg * 8;
    srcB[c] = Wb + (size_t)(e0 + row) * KDIM + ccg * 8;
    dstOff[c] = s * 8;                        // linear LDS (ushorts)
  }

  // loop-invariant swizzled fragment offsets (ushorts within ring slot)
  int aofs[8], bofs[4];
#pragma unroll
  for (int mt = 0; mt < 8; ++mt) {
    const int row = wm + mt * 16 + l15;
    aofs[mt] = row * 32 + ((quad ^ ((row >> 1) & 3)) * 8);
  }
#pragma unroll
  for (int nt = 0; nt < 4; ++nt) {
    const int row = wn + nt * 16 + l15;
    bofs[nt] = 8192 + row * 32 + ((quad ^ ((row >> 1) & 3)) * 8);
  }

  auto STAGE_A = [&](int t) {
    const int rb_ = (t & 3) * 16384;
    const int k0_ = t * 32;
#pragma unroll
    for (int c = 0; c < 2; ++c)
      gload_lds16(srcA[c] + k0_, &lds[rb_ + dstOff[c]]);
  };
  auto STAGE_B = [&](int t) {
    const int rb_ = (t & 3) * 16384;
    const int k0_ = t * 32;
#pragma unroll
    for (int c = 0; c < 2; ++c)
      gload_lds16(srcB[c] + k0_, &lds[rb_ + 8192 + dstOff[c]]);
  };

  short8 Ax[4], Bx[4], Ay[4], By[4], A47[4];

  // prologue: fill 3 ring slots (12 loads); vmcnt(8) -> slot 0 landed.
  STAGE_A(0); STAGE_B(0);
  STAGE_A(1); STAGE_B(1);
  STAGE_A(2); STAGE_B(2);
  __builtin_amdgcn_sched_barrier(0);
  asm volatile("s_waitcnt vmcnt(8)" ::: "memory");
  __builtin_amdgcn_sched_barrier(0);
  __builtin_amdgcn_s_barrier();
  __builtin_amdgcn_sched_barrier(0);
  // pre-read step-0 a03,b from slot 0 into the even-parity set
#pragma unroll
  for (int mt = 0; mt < 4; ++mt) Ax[mt] = *(const short8*)&lds[aofs[mt]];
#pragma unroll
  for (int nt = 0; nt < 4; ++nt) Bx[nt] = *(const short8*)&lds[bofs[nt]];

#define STEP(T, AC, BC, AN, BN)                                               \
  {                                                                           \
    const int rb = ((T) & 3) * 16384;                                         \
    const int rbn = (((T) + 1) & 3) * 16384;                                  \
    _Pragma("unroll")                                                         \
    for (int mt = 0; mt < 4; ++mt)                                            \
      A47[mt] = *(const short8*)&lds[rb + aofs[4 + mt]];                      \
    if ((T) + 3 < 64) STAGE_A((T) + 3);                                       \
    __builtin_amdgcn_sched_barrier(0);                                        \
    if ((T) + 3 < 64) {                                                       \
      asm volatile("s_waitcnt vmcnt(6)" ::: "memory");                        \
    } else if ((T) + 2 < 64) {                                                \
      asm volatile("s_waitcnt vmcnt(4)" ::: "memory");                        \
    } else if ((T) + 1 < 64) {                                                \
      asm volatile("s_waitcnt vmcnt(0)" ::: "memory");                        \
    }                                                                         \
    __builtin_amdgcn_sched_barrier(0);                                        \
    __builtin_amdgcn_s_barrier();                                             \
    asm volatile("s_waitcnt lgkmcnt(4)" ::: "memory");                        \
    __builtin_amdgcn_sched_barrier(0);                                        \
    __builtin_amdgcn_s_setprio(1);                                            \
    _Pragma("unroll")                                                         \
    for (int mt = 0; mt < 4; ++mt)                                            \
      _Pragma("unroll")                                                       \
      for (int nt = 0; nt < 4; ++nt)                                          \
        acc[mt][nt] = __builtin_amdgcn_mfma_f32_16x16x32_bf16(                \
            AC[mt], BC[nt], acc[mt][nt], 0, 0, 0);                            \
    __builtin_amdgcn_s_setprio(0);                                            \
    __builtin_amdgcn_sched_barrier(0);                                        \
    if ((T) < 63) {                                                           \
      _Pragma("unroll")                                                       \
      for (int mt = 0; mt < 4; ++mt)                                          \
        AN[mt] = *(const short8*)&lds[rbn + aofs[mt]];                        \
      _Pragma("unroll")                                                       \
      for (int nt = 0; nt < 4; ++nt)                                          \
        BN[nt] = *(const short8*)&lds[rbn + bofs[nt]];                        \
    }                                                                         \
    if ((T) + 3 < 64) STAGE_B((T) + 3);                                       \
    __builtin_amdgcn_sched_barrier(0);                                        \
    if ((T) < 63) {                                                           \
      asm volatile("s_waitcnt lgkmcnt(8)" ::: "memory");                      \
    } else {                                                                  \
      asm volatile("s_waitcnt lgkmcnt(0)" ::: "memory");                      \
    }                                                                         \
    __builtin_amdgcn_sched_barrier(0);                                        \
    __builtin_amdgcn_s_barrier();                                             \
    __builtin_amdgcn_sched_barrier(0);                                        \
    __builtin_amdgcn_s_setprio(1);                                            \
    _Pragma("unroll")                                                         \
    for (int mt = 0; mt < 4; ++mt)                                            \
      _Pragma("unroll")                                                       \
      for (int nt = 0; nt < 4; ++nt)                                          \
        acc[4 + mt][nt] = __builtin_amdgcn_mfma_f32_16x16x32_bf16(            \
            A47[mt], BC[nt], acc[4 + mt][nt], 0, 0, 0);                       \
    __builtin_amdgcn_s_setprio(0);                                            \
    __builtin_amdgcn_sched_barrier(0);                                        \
  }

  for (int t = 0; t < 64; t += 2) {
    STEP(t, Ax, Bx, Ay, By)
    STEP(t + 1, Ay, By, Ax, Bx)
  }
#undef STEP

  if (be < 16) {
#pragma unroll
    for (int mt = 0; mt < 8; ++mt)
#pragma unroll
      for (int nt = 0; nt < 4; ++nt) {
        const int col = e0 + wn + nt * 16 + l15;
#pragma unroll
        for (int r = 0; r < 4; ++r) {
          const int rowg = m0 + wm + mt * 16 + quad * 4 + r;
          Cproj[(size_t)rowg * EPROJ + col] = f2bf(acc[mt][nt][r]);
        }
      }
  } else {
    unsigned short* Gt = (be < 24) ? Gbt : Gat;
    const int fb = e0 - ((be < 24) ? 4096 : 6144);
#pragma unroll
    for (int mt = 0; mt < 8; ++mt)
#pragma unroll
      for (int nt = 0; nt < 4; ++nt) {
        const int f = fb + wn + nt * 16 + l15;
        const int tok0 = m0 + wm + mt * 16 + quad * 4;
        ushort4 o;
        o.x = f2bf(acc[mt][nt][0]); o.y = f2bf(acc[mt][nt][1]);
        o.z = f2bf(acc[mt][nt][2]); o.w = f2bf(acc[mt][nt][3]);
        *(ushort4*)&Gt[(size_t)f * BT + tok0] = o;
      }
  }
}

// ---------------------------------------------------------------------------
// Kernel C: score partials via MFMA. grid (16 batches, 2 branches, 4 K-chunks).
// Spart[(br*16+b)*4+kc][i][j] (fp32, unmasked, unscaled).
// ---------------------------------------------------------------------------
__global__ __launch_bounds__(256) void score_kernel(
    const unsigned short* __restrict__ Cproj, float* __restrict__ Spart) {
  const int b = blockIdx.x;
  const int br = blockIdx.y;
  const int kc = blockIdx.z;
  const int aoff = br ? 2048 : 0;   // ta : tb
  const int boff = aoff + 1024;     // pa : pb

  __shared__ __align__(16) unsigned short As[128 * 32];
  __shared__ __align__(16) unsigned short Bs[128 * 32];
  const int tid = threadIdx.x;
  const int lane = tid & 63;
  const int w = tid >> 6;
  const int wm = (w >> 1) * 64;
  const int wn = (w & 1) * 64;
  const int quad = lane >> 4;
  const int l15 = lane & 15;
  const int t0 = b * T_SZ;

  floatx4 acc[4][4];
#pragma unroll
  for (int mt = 0; mt < 4; ++mt)
#pragma unroll
    for (int nt = 0; nt < 4; ++nt) {
      floatx4 z = {0.f, 0.f, 0.f, 0.f};
      acc[mt][nt] = z;
    }

  const unsigned short* gA[2];
  const unsigned short* gB[2];
  unsigned short* lA[2];
  unsigned short* lB[2];
#pragma unroll
  for (int c = 0; c < 2; ++c) {
    const int s = w * 64 + lane + c * 256;
    const int row = s >> 2;
    const int ccg = (s & 3) ^ ((row >> 1) & 3);
    gA[c] = Cproj + (size_t)(t0 + row) * EPROJ + aoff + ccg * 8;
    gB[c] = Cproj + (size_t)(t0 + row) * EPROJ + boff + ccg * 8;
    lA[c] = &As[(size_t)s * 8];
    lB[c] = &Bs[(size_t)s * 8];
  }

  int aofs[4], bofs[4];
#pragma unroll
  for (int mt = 0; mt < 4; ++mt) {
    const int row = wm + mt * 16 + l15;
    aofs[mt] = row * 32 + ((quad ^ ((row >> 1) & 3)) * 8);
  }
#pragma unroll
  for (int nt = 0; nt < 4; ++nt) {
    const int row = wn + nt * 16 + l15;
    bofs[nt] = row * 32 + ((quad ^ ((row >> 1) & 3)) * 8);
  }

  const int kbeg = kc * 256;
  for (int k0 = kbeg; k0 < kbeg + 256; k0 += 32) {
#pragma unroll
    for (int c = 0; c < 2; ++c) {
      gload_lds16(gA[c] + k0, lA[c]);
      gload_lds16(gB[c] + k0, lB[c]);
    }
    __syncthreads();
    short8 a[4], bb[4];
#pragma unroll
    for (int mt = 0; mt < 4; ++mt) a[mt] = *(const short8*)&As[aofs[mt]];
#pragma unroll
    for (int nt = 0; nt < 4; ++nt) bb[nt] = *(const short8*)&Bs[bofs[nt]];
#pragma unroll
    for (int mt = 0; mt < 4; ++mt)
#pragma unroll
      for (int nt = 0; nt < 4; ++nt)
        acc[mt][nt] = __builtin_amdgcn_mfma_f32_16x16x32_bf16(
            a[mt], bb[nt], acc[mt][nt], 0, 0, 0);
    __syncthreads();
  }

  float* Sp = Spart + ((size_t)(br * B_SZ + b) * 4 + kc) * T_SZ * T_SZ;
#pragma unroll
  for (int mt = 0; mt < 4; ++mt)
#pragma unroll
    for (int nt = 0; nt < 4; ++nt) {
      const int j = wn + nt * 16 + l15;
#pragma unroll
      for (int r = 0; r < 4; ++r) {
        const int i = wm + mt * 16 + quad * 4 + r;
        Sp[(size_t)i * T_SZ + j] = acc[mt][nt][r];
      }
    }
}

// ---------------------------------------------------------------------------
// Combine: Sbf = f2bf(mask * scale * sum_kc Spart). 512 blocks x 256 thr,
// one j4-group (4 cols) per thread.
// ---------------------------------------------------------------------------
__global__ __launch_bounds__(256) void score_combine(
    const float* __restrict__ Spart, unsigned short* __restrict__ Sbf) {
  const float scale = 0.022097086912079608f;  // 1/sqrt(2*1024)
  const int gid = blockIdx.x * 256 + threadIdx.x;   // < 131072
  const int j4 = gid & 31;
  const int i = (gid >> 5) & 127;
  const int bb = (gid >> 12) & 15;
  const int br = gid >> 16;
  const size_t base = ((size_t)(br * B_SZ + bb) * 4) * T_SZ * T_SZ +
                      (size_t)i * T_SZ + j4 * 4;
  float4 s = {0.f, 0.f, 0.f, 0.f};
#pragma unroll
  for (int kc = 0; kc < 4; ++kc) {
    const float4 v = *(const float4*)&Spart[base + (size_t)kc * T_SZ * T_SZ];
    s.x += v.x; s.y += v.y; s.z += v.z; s.w += v.w;
  }
  const int j0 = j4 * 4;
  ushort4 o;
  o.x = f2bf((br ? (j0 + 0 > i) : (j0 + 0 < i)) ? s.x * scale : 0.f);
  o.y = f2bf((br ? (j0 + 1 > i) : (j0 + 1 < i)) ? s.y * scale : 0.f);
  o.z = f2bf((br ? (j0 + 2 > i) : (j0 + 2 < i)) ? s.z * scale : 0.f);
  o.w = f2bf((br ? (j0 + 3 > i) : (j0 + 3 < i)) ? s.w * scale : 0.f);
  *(ushort4*)&Sbf[((size_t)(br * B_SZ + bb)) * T_SZ * T_SZ +
                  (size_t)i * T_SZ + j0] = o;
}

// ---------------------------------------------------------------------------
// Kernel D: PV via MFMA, no LDS.
// ---------------------------------------------------------------------------
__global__ __launch_bounds__(256) void pv_mfma(
    const unsigned short* __restrict__ Nbf,
    const unsigned short* __restrict__ Sbf,
    const unsigned short* __restrict__ Gbt,
    const unsigned short* __restrict__ Gat,
    float* __restrict__ out) {
  const int ft = blockIdx.x;
  const int b = blockIdx.y;
  const int f0 = ft * 128;
  const int t0 = b * T_SZ;
  const int tid = threadIdx.x;
  const int lane = tid & 63;
  const int w = tid >> 6;
  const int wm = (w >> 1) * 64;   // token dim
  const int wn = (w & 1) * 64;    // f dim
  const int quad = lane >> 4;
  const int l15 = lane & 15;

  const unsigned short* Sb = Sbf + ((size_t)0 * B_SZ + b) * T_SZ * T_SZ;
  const unsigned short* Sa = Sbf + ((size_t)1 * B_SZ + b) * T_SZ * T_SZ;

  floatx4 acc[4][4];
#pragma unroll
  for (int mt = 0; mt < 4; ++mt)
#pragma unroll
    for (int nt = 0; nt < 4; ++nt) {
      floatx4 z = {0.f, 0.f, 0.f, 0.f};
      acc[mt][nt] = z;
    }

#pragma unroll
  for (int k0 = 0; k0 < T_SZ; k0 += 32) {
    short8 ab[4], aa[4], bb[4], ba[4];
#pragma unroll
    for (int mt = 0; mt < 4; ++mt) {
      const int i = wm + mt * 16 + l15;
      ab[mt] = *(const short8*)&Sb[(size_t)i * T_SZ + k0 + quad * 8];
      aa[mt] = *(const short8*)&Sa[(size_t)i * T_SZ + k0 + quad * 8];
    }
#pragma unroll
    for (int nt = 0; nt < 4; ++nt) {
      const int f = f0 + wn + nt * 16 + l15;
      bb[nt] = *(const short8*)&Gbt[(size_t)f * BT + t0 + k0 + quad * 8];
      ba[nt] = *(const short8*)&Gat[(size_t)f * BT + t0 + k0 + quad * 8];
    }
#pragma unroll
    for (int mt = 0; mt < 4; ++mt)
#pragma unroll
      for (int nt = 0; nt < 4; ++nt) {
        acc[mt][nt] = __builtin_amdgcn_mfma_f32_16x16x32_bf16(
            ab[mt], bb[nt], acc[mt][nt], 0, 0, 0);
        acc[mt][nt] = __builtin_amdgcn_mfma_f32_16x16x32_bf16(
            aa[mt], ba[nt], acc[mt][nt], 0, 0, 0);
      }
  }

#pragma unroll
  for (int mt = 0; mt < 4; ++mt)
#pragma unroll
    for (int nt = 0; nt < 4; ++nt) {
      const int f = f0 + wn + nt * 16 + l15;
#pragma unroll
      for (int r = 0; r < 4; ++r) {
        const int tok = t0 + wm + mt * 16 + quad * 4 + r;
        out[(size_t)tok * D2_SZ + f] =
            acc[mt][nt][r] + bf2f(Nbf[(size_t)tok * D2_SZ + f]);
      }
    }
}

// ---------------------------------------------------------------------------
extern "C" void kernel_launch(void* const* d_in, const int* in_sizes, int n_in,
                              void* d_out, int out_size, void* d_ws, size_t ws_size,
                              hipStream_t stream) {
  const float* feat = (const float*)d_in[0];
  const float* Wq  = (const float*)d_in[1];
  const float* Wtb = (const float*)d_in[2];
  const float* Wpb = (const float*)d_in[3];
  const float* Wgb = (const float*)d_in[4];  // dict order: gb before ta
  const float* Wta = (const float*)d_in[5];
  const float* Wpa = (const float*)d_in[6];
  const float* Wga = (const float*)d_in[7];
  float* out = (float*)d_out;

  unsigned short* ws = (unsigned short*)d_ws;
  unsigned short* Nbf   = ws;                                 // [2048][2048] bf16
  unsigned short* Wb    = Nbf + (size_t)BT * D2_SZ;           // [8192][2048] bf16
  unsigned short* Cproj = Wb + (size_t)EALL * KDIM;           // [2048][4096] bf16
  unsigned short* Gbt   = Cproj + (size_t)BT * EPROJ;         // [2048][2048] bf16
  unsigned short* Gat   = Gbt + (size_t)D2_SZ * BT;           // [2048][2048] bf16
  unsigned short* Sbf   = Gat + (size_t)D2_SZ * BT;           // [2][16][128][128] bf16
  float* Spart = (float*)(Sbf + (size_t)2 * B_SZ * T_SZ * T_SZ); // [2][16][4][128][128] f32

  build_n_kernel<<<BT, 256, 0, stream>>>(feat, Wq, Nbf);
  cvt_all<<<dim3(2048, 6), 256, 0, stream>>>(Wtb, Wpb, Wta, Wpa, Wgb, Wga, Wb);
  gemm_fused<<<dim3(256), 512, 0, stream>>>(Nbf, Wb, Cproj, Gbt, Gat);
  score_kernel<<<dim3(B_SZ, 2, 4), 256, 0, stream>>>(Cproj, Spart);
  score_combine<<<512, 256, 0, stream>>>(Spart, Sbf);
  pv_mfma<<<dim3(D2_SZ / 128, B_SZ), 256, 0, stream>>>(Nbf, Sbf, Gbt, Gat, out);
}

// Round 4
// 298.785 us; speedup vs baseline: 1.0137x; 1.0067x over previous
//
#include <hip/hip_runtime.h>
#include <hip/hip_bf16.h>
#include <math.h>

#define B_SZ 16
#define T_SZ 128
#define N_P 12
#define D_SZ 1024
#define D2_SZ 2048
#define BT 2048          // B*T tokens
#define KDIM 2048        // inner dim of projections (2D)
#define EALL 8192        // 4*1024 (tb,pb,ta,pa) + 2*2048 (gb,ga)
#define EPROJ 4096       // tb|pb|ta|pa row width

typedef __attribute__((ext_vector_type(8))) short short8;    // 8 bf16 = 4 VGPRs
typedef __attribute__((ext_vector_type(4))) float floatx4;   // MFMA C/D

__device__ inline void gload_lds16(const void* g, void* l) {
  __builtin_amdgcn_global_load_lds(
      (const __attribute__((address_space(1))) void*)g,
      (__attribute__((address_space(3))) void*)l, 16, 0, 0);
}

__device__ inline unsigned short f2bf(float x) {
  union { __hip_bfloat16 h; unsigned short u; } cv;
  cv.h = __float2bfloat16(x);
  return cv.u;
}
__device__ inline float bf2f(unsigned short u) {
  return __uint_as_float(((unsigned)u) << 16);
}

// ---------------------------------------------------------------------------
// Kernel 1 (merged): blocks [0, BT) build n = [g ; max] per token;
// blocks [BT, BT+12288) convert the 6 weight matrices to bf16.
// Wb row order: [tb | pb | ta | pa | gb | ga]
// ---------------------------------------------------------------------------
__global__ __launch_bounds__(256) void prep_kernel(
    const float* __restrict__ feat, const float* __restrict__ Wq,
    const float* __restrict__ Wtb, const float* __restrict__ Wpb,
    const float* __restrict__ Wta, const float* __restrict__ Wpa,
    const float* __restrict__ Wgb, const float* __restrict__ Wga,
    unsigned short* __restrict__ Nbf, unsigned short* __restrict__ Wb) {
  const int bid = blockIdx.x;
  const int tid = threadIdx.x;
  if (bid < BT) {
    // ---------------- build_n ----------------
    const int t = bid;
    const float4* fb4 = (const float4*)(feat + (size_t)t * N_P * D_SZ);
    const float4* wq4 = (const float4*)Wq;

    float4 q = {0.f, 0.f, 0.f, 0.f};
#pragma unroll
    for (int m = 0; m < N_P; ++m) {
      const float4 v = wq4[m * 256 + tid];
      q.x += v.x; q.y += v.y; q.z += v.z; q.w += v.w;
    }

    float4 fv[N_P];
    float part[N_P];
#pragma unroll
    for (int n = 0; n < N_P; ++n) {
      const float4 f = fb4[n * 256 + tid];
      fv[n] = f;
      part[n] = f.x * q.x + f.y * q.y + f.z * q.z + f.w * q.w;
    }

    __shared__ float wred[N_P * 4];
    const int lane = tid & 63;
    const int wave = tid >> 6;
#pragma unroll
    for (int n = 0; n < N_P; ++n) {
      float v = part[n];
#pragma unroll
      for (int off = 32; off; off >>= 1) v += __shfl_down(v, off);
      if (lane == 0) wred[n * 4 + wave] = v;
    }
    __syncthreads();

    float w[N_P];
#pragma unroll
    for (int n = 0; n < N_P; ++n)
      w[n] = wred[n * 4 + 0] + wred[n * 4 + 1] + wred[n * 4 + 2] +
             wred[n * 4 + 3];

    float4 g = {0.f, 0.f, 0.f, 0.f};
    float4 fm = {-INFINITY, -INFINITY, -INFINITY, -INFINITY};
#pragma unroll
    for (int n = 0; n < N_P; ++n) {
      const float4 f = fv[n];
      g.x += w[n] * f.x; g.y += w[n] * f.y; g.z += w[n] * f.z;
      g.w += w[n] * f.w;
      fm.x = fmaxf(fm.x, f.x); fm.y = fmaxf(fm.y, f.y);
      fm.z = fmaxf(fm.z, f.z); fm.w = fmaxf(fm.w, f.w);
    }
    ushort4 og, of;
    og.x = f2bf(g.x); og.y = f2bf(g.y); og.z = f2bf(g.z); og.w = f2bf(g.w);
    of.x = f2bf(fm.x); of.y = f2bf(fm.y); of.z = f2bf(fm.z); of.w = f2bf(fm.w);
    *(ushort4*)&Nbf[(size_t)t * D2_SZ + tid * 4] = og;
    *(ushort4*)&Nbf[(size_t)t * D2_SZ + D_SZ + tid * 4] = of;
  } else {
    // ---------------- weight conversion ----------------
    const int id = bid - BT;            // 0..12287
    const int r = id >> 11;             // 0..5
    const int xb = id & 2047;
    const int i = xb * 256 + tid;       // < 524288
    const float* src;
    size_t off;
    switch (r) {
      case 0: src = Wtb; off = 0; break;
      case 1: src = Wpb; off = (size_t)1024 * KDIM; break;
      case 2: src = Wta; off = (size_t)2048 * KDIM; break;
      case 3: src = Wpa; off = (size_t)3072 * KDIM; break;
      case 4: src = Wgb; off = (size_t)4096 * KDIM; break;
      default: src = Wga; off = (size_t)6144 * KDIM; break;
    }
    {
      const float4 v = ((const float4*)src)[i];
      ushort4 o;
      o.x = f2bf(v.x); o.y = f2bf(v.y); o.z = f2bf(v.z); o.w = f2bf(v.w);
      ((ushort4*)(Wb + off))[i] = o;
    }
    if (r >= 4) {
      const int i2 = i + 524288;
      const float4 v = ((const float4*)src)[i2];
      ushort4 o;
      o.x = f2bf(v.x); o.y = f2bf(v.y); o.z = f2bf(v.z); o.w = f2bf(v.w);
      ((ushort4*)(Wb + off))[i2] = o;
    }
  }
}

// ---------------------------------------------------------------------------
// Kernel B: fused projection GEMM, bf16 MFMA.  (round-1 verified schedule)
// 256x256 tile, BK=32, 8 waves (2M x 4N), ring-of-4 LDS pipeline (prefetch
// distance 3) with counted vmcnt(8) -> barrier (T3+T4), setprio around MFMA
// (T5), bijective XCD swizzle (T1), LDS XOR swizzle (T2).
// ---------------------------------------------------------------------------
__global__ __launch_bounds__(512, 2) void gemm_fused(
    const unsigned short* __restrict__ X,
    const unsigned short* __restrict__ Wb,
    unsigned short* __restrict__ Cproj,
    unsigned short* __restrict__ Gbt,
    unsigned short* __restrict__ Gat) {
  __shared__ __align__(16) unsigned short lds[4 * 16384];  // 128 KiB ring
  const int tid = threadIdx.x;
  const int lane = tid & 63;
  const int w = tid >> 6;           // 0..7
  const int quad = lane >> 4;
  const int l15 = lane & 15;
  const int wm = (w >> 2) * 128;    // wave row (2 waves in M)
  const int wn = (w & 3) * 64;      // wave col (4 waves in N)

  const int bid = blockIdx.x;
  const int swz = (bid & 7) * 32 + (bid >> 3);
  const int m0 = (swz & 7) * 256;   // token tile
  const int be = swz >> 3;          // 0..31 E-tile
  const int e0 = be * 256;

  floatx4 acc[8][4];
#pragma unroll
  for (int mt = 0; mt < 8; ++mt)
#pragma unroll
    for (int nt = 0; nt < 4; ++nt) {
      floatx4 z = {0.f, 0.f, 0.f, 0.f};
      acc[mt][nt] = z;
    }

  const unsigned short* srcA[2];
  const unsigned short* srcB[2];
  int dstOff[2];
#pragma unroll
  for (int c = 0; c < 2; ++c) {
    const int s = tid + c * 512;              // slot 0..1023
    const int row = s >> 2;                   // 0..255
    const int ccg = (s & 3) ^ ((row >> 1) & 3);  // swizzled source chunk
    srcA[c] = X + (size_t)(m0 + row) * KDIM + ccg * 8;
    srcB[c] = Wb + (size_t)(e0 + row) * KDIM + ccg * 8;
    dstOff[c] = s * 8;                        // linear LDS (ushorts)
  }

  int aofs[8], bofs[4];
#pragma unroll
  for (int mt = 0; mt < 8; ++mt) {
    const int row = wm + mt * 16 + l15;
    aofs[mt] = row * 32 + ((quad ^ ((row >> 1) & 3)) * 8);
  }
#pragma unroll
  for (int nt = 0; nt < 4; ++nt) {
    const int row = wn + nt * 16 + l15;
    bofs[nt] = 8192 + row * 32 + ((quad ^ ((row >> 1) & 3)) * 8);
  }

  auto STAGE = [&](int t) {
    const int rb_ = (t & 3) * 16384;
    const int k0_ = t * 32;
#pragma unroll
    for (int c = 0; c < 2; ++c) {
      gload_lds16(srcA[c] + k0_, &lds[rb_ + dstOff[c]]);
      gload_lds16(srcB[c] + k0_, &lds[rb_ + 8192 + dstOff[c]]);
    }
  };

  STAGE(0); STAGE(1); STAGE(2);
  __builtin_amdgcn_sched_barrier(0);
  asm volatile("s_waitcnt vmcnt(8)" ::: "memory");
  __builtin_amdgcn_sched_barrier(0);
  __builtin_amdgcn_s_barrier();
  __builtin_amdgcn_sched_barrier(0);

  for (int t = 0; t < 64; ++t) {            // KDIM/32 = 64 steps
    const int rb = (t & 3) * 16384;
    short8 a[8], b[4];
#pragma unroll
    for (int mt = 0; mt < 8; ++mt) a[mt] = *(const short8*)&lds[rb + aofs[mt]];
#pragma unroll
    for (int nt = 0; nt < 4; ++nt) b[nt] = *(const short8*)&lds[rb + bofs[nt]];
    if (t + 3 < 64) STAGE(t + 3);
    __builtin_amdgcn_s_setprio(1);
#pragma unroll
    for (int mt = 0; mt < 8; ++mt)
#pragma unroll
      for (int nt = 0; nt < 4; ++nt)
        acc[mt][nt] = __builtin_amdgcn_mfma_f32_16x16x32_bf16(
            a[mt], b[nt], acc[mt][nt], 0, 0, 0);
    __builtin_amdgcn_s_setprio(0);
    __builtin_amdgcn_sched_barrier(0);
    if (t + 3 < 64) {
      asm volatile("s_waitcnt vmcnt(8)" ::: "memory");
    } else if (t + 2 < 64) {
      asm volatile("s_waitcnt vmcnt(4)" ::: "memory");
    } else if (t + 1 < 64) {
      asm volatile("s_waitcnt vmcnt(0)" ::: "memory");
    }
    __builtin_amdgcn_sched_barrier(0);
    __builtin_amdgcn_s_barrier();
    __builtin_amdgcn_sched_barrier(0);
  }

  if (be < 16) {
#pragma unroll
    for (int mt = 0; mt < 8; ++mt)
#pragma unroll
      for (int nt = 0; nt < 4; ++nt) {
        const int col = e0 + wn + nt * 16 + l15;
#pragma unroll
        for (int r = 0; r < 4; ++r) {
          const int rowg = m0 + wm + mt * 16 + quad * 4 + r;
          Cproj[(size_t)rowg * EPROJ + col] = f2bf(acc[mt][nt][r]);
        }
      }
  } else {
    unsigned short* Gt = (be < 24) ? Gbt : Gat;
    const int fb = e0 - ((be < 24) ? 4096 : 6144);
#pragma unroll
    for (int mt = 0; mt < 8; ++mt)
#pragma unroll
      for (int nt = 0; nt < 4; ++nt) {
        const int f = fb + wn + nt * 16 + l15;
        const int tok0 = m0 + wm + mt * 16 + quad * 4;
        ushort4 o;
        o.x = f2bf(acc[mt][nt][0]); o.y = f2bf(acc[mt][nt][1]);
        o.z = f2bf(acc[mt][nt][2]); o.w = f2bf(acc[mt][nt][3]);
        *(ushort4*)&Gt[(size_t)f * BT + tok0] = o;
      }
  }
}

// ---------------------------------------------------------------------------
// Kernel 3: fused score. grid (16 batches, 2 branches, 2 j-chunks).
// Each block: 128(i) x 64(j) S-tile, full K=1024, epilogue mask+scale+bf16.
// Eliminates the fp32 Spart roundtrip and the combine kernel.
// ---------------------------------------------------------------------------
__global__ __launch_bounds__(256) void score_direct(
    const unsigned short* __restrict__ Cproj, unsigned short* __restrict__ Sbf) {
  const int b = blockIdx.x;
  const int br = blockIdx.y;
  const int jc = blockIdx.z;
  const int aoff = br ? 2048 : 0;   // ta : tb
  const int boff = aoff + 1024;     // pa : pb
  const int t0 = b * T_SZ;
  const int j0 = jc * 64;

  __shared__ __align__(16) unsigned short As[128 * 32];   // 8 KB
  __shared__ __align__(16) unsigned short Bs[64 * 32];    // 4 KB
  const int tid = threadIdx.x;
  const int lane = tid & 63;
  const int w = tid >> 6;
  const int wm = (w >> 1) * 64;    // i-offset (2 waves in M)
  const int wn = (w & 1) * 32;     // j-offset (2 waves in N)
  const int quad = lane >> 4;
  const int l15 = lane & 15;

  floatx4 acc[4][2];
#pragma unroll
  for (int mt = 0; mt < 4; ++mt)
#pragma unroll
    for (int nt = 0; nt < 2; ++nt) {
      floatx4 z = {0.f, 0.f, 0.f, 0.f};
      acc[mt][nt] = z;
    }

  // A staging: 512 slots (128 rows x 4 chunks), 2 per thread.
  const unsigned short* gA[2];
  unsigned short* lA[2];
#pragma unroll
  for (int c = 0; c < 2; ++c) {
    const int s = tid + c * 256;
    const int row = s >> 2;
    const int ccg = (s & 3) ^ ((row >> 1) & 3);
    gA[c] = Cproj + (size_t)(t0 + row) * EPROJ + aoff + ccg * 8;
    lA[c] = &As[(size_t)s * 8];
  }
  // B staging: 256 slots (64 rows x 4 chunks), 1 per thread.
  const unsigned short* gB;
  unsigned short* lB;
  {
    const int s = tid;
    const int row = s >> 2;
    const int ccg = (s & 3) ^ ((row >> 1) & 3);
    gB = Cproj + (size_t)(t0 + j0 + row) * EPROJ + boff + ccg * 8;
    lB = &Bs[(size_t)s * 8];
  }

  int aofs[4], bofs[2];
#pragma unroll
  for (int mt = 0; mt < 4; ++mt) {
    const int row = wm + mt * 16 + l15;
    aofs[mt] = row * 32 + ((quad ^ ((row >> 1) & 3)) * 8);
  }
#pragma unroll
  for (int nt = 0; nt < 2; ++nt) {
    const int row = wn + nt * 16 + l15;
    bofs[nt] = row * 32 + ((quad ^ ((row >> 1) & 3)) * 8);
  }

  for (int k0 = 0; k0 < D_SZ; k0 += 32) {   // K = 1024, 32 steps
    gload_lds16(gA[0] + k0, lA[0]);
    gload_lds16(gA[1] + k0, lA[1]);
    gload_lds16(gB + k0, lB);
    __syncthreads();
    short8 a[4], bb[2];
#pragma unroll
    for (int mt = 0; mt < 4; ++mt) a[mt] = *(const short8*)&As[aofs[mt]];
#pragma unroll
    for (int nt = 0; nt < 2; ++nt) bb[nt] = *(const short8*)&Bs[bofs[nt]];
#pragma unroll
    for (int mt = 0; mt < 4; ++mt)
#pragma unroll
      for (int nt = 0; nt < 2; ++nt)
        acc[mt][nt] = __builtin_amdgcn_mfma_f32_16x16x32_bf16(
            a[mt], bb[nt], acc[mt][nt], 0, 0, 0);
    __syncthreads();
  }

  const float scale = 0.022097086912079608f;  // 1/sqrt(2*1024)
  unsigned short* Sp = Sbf + ((size_t)(br * B_SZ + b)) * T_SZ * T_SZ;
#pragma unroll
  for (int mt = 0; mt < 4; ++mt)
#pragma unroll
    for (int nt = 0; nt < 2; ++nt) {
      const int j = j0 + wn + nt * 16 + l15;
#pragma unroll
      for (int r = 0; r < 4; ++r) {
        const int i = wm + mt * 16 + quad * 4 + r;
        const bool keep = br ? (j > i) : (j < i);
        Sp[(size_t)i * T_SZ + j] = f2bf(keep ? acc[mt][nt][r] * scale : 0.f);
      }
    }
}

// ---------------------------------------------------------------------------
// Kernel D: PV via MFMA, no LDS.
// ---------------------------------------------------------------------------
__global__ __launch_bounds__(256) void pv_mfma(
    const unsigned short* __restrict__ Nbf,
    const unsigned short* __restrict__ Sbf,
    const unsigned short* __restrict__ Gbt,
    const unsigned short* __restrict__ Gat,
    float* __restrict__ out) {
  const int ft = blockIdx.x;
  const int b = blockIdx.y;
  const int f0 = ft * 128;
  const int t0 = b * T_SZ;
  const int tid = threadIdx.x;
  const int lane = tid & 63;
  const int w = tid >> 6;
  const int wm = (w >> 1) * 64;   // token dim
  const int wn = (w & 1) * 64;    // f dim
  const int quad = lane >> 4;
  const int l15 = lane & 15;

  const unsigned short* Sb = Sbf + ((size_t)0 * B_SZ + b) * T_SZ * T_SZ;
  const unsigned short* Sa = Sbf + ((size_t)1 * B_SZ + b) * T_SZ * T_SZ;

  floatx4 acc[4][4];
#pragma unroll
  for (int mt = 0; mt < 4; ++mt)
#pragma unroll
    for (int nt = 0; nt < 4; ++nt) {
      floatx4 z = {0.f, 0.f, 0.f, 0.f};
      acc[mt][nt] = z;
    }

#pragma unroll
  for (int k0 = 0; k0 < T_SZ; k0 += 32) {
    short8 ab[4], aa[4], bb[4], ba[4];
#pragma unroll
    for (int mt = 0; mt < 4; ++mt) {
      const int i = wm + mt * 16 + l15;
      ab[mt] = *(const short8*)&Sb[(size_t)i * T_SZ + k0 + quad * 8];
      aa[mt] = *(const short8*)&Sa[(size_t)i * T_SZ + k0 + quad * 8];
    }
#pragma unroll
    for (int nt = 0; nt < 4; ++nt) {
      const int f = f0 + wn + nt * 16 + l15;
      bb[nt] = *(const short8*)&Gbt[(size_t)f * BT + t0 + k0 + quad * 8];
      ba[nt] = *(const short8*)&Gat[(size_t)f * BT + t0 + k0 + quad * 8];
    }
#pragma unroll
    for (int mt = 0; mt < 4; ++mt)
#pragma unroll
      for (int nt = 0; nt < 4; ++nt) {
        acc[mt][nt] = __builtin_amdgcn_mfma_f32_16x16x32_bf16(
            ab[mt], bb[nt], acc[mt][nt], 0, 0, 0);
        acc[mt][nt] = __builtin_amdgcn_mfma_f32_16x16x32_bf16(
            aa[mt], ba[nt], acc[mt][nt], 0, 0, 0);
      }
  }

#pragma unroll
  for (int mt = 0; mt < 4; ++mt)
#pragma unroll
    for (int nt = 0; nt < 4; ++nt) {
      const int f = f0 + wn + nt * 16 + l15;
#pragma unroll
      for (int r = 0; r < 4; ++r) {
        const int tok = t0 + wm + mt * 16 + quad * 4 + r;
        out[(size_t)tok * D2_SZ + f] =
            acc[mt][nt][r] + bf2f(Nbf[(size_t)tok * D2_SZ + f]);
      }
    }
}

// ---------------------------------------------------------------------------
extern "C" void kernel_launch(void* const* d_in, const int* in_sizes, int n_in,
                              void* d_out, int out_size, void* d_ws, size_t ws_size,
                              hipStream_t stream) {
  const float* feat = (const float*)d_in[0];
  const float* Wq  = (const float*)d_in[1];
  const float* Wtb = (const float*)d_in[2];
  const float* Wpb = (const float*)d_in[3];
  const float* Wgb = (const float*)d_in[4];  // dict order: gb before ta
  const float* Wta = (const float*)d_in[5];
  const float* Wpa = (const float*)d_in[6];
  const float* Wga = (const float*)d_in[7];
  float* out = (float*)d_out;

  unsigned short* ws = (unsigned short*)d_ws;
  unsigned short* Nbf   = ws;                                 // [2048][2048] bf16
  unsigned short* Wb    = Nbf + (size_t)BT * D2_SZ;           // [8192][2048] bf16
  unsigned short* Cproj = Wb + (size_t)EALL * KDIM;           // [2048][4096] bf16
  unsigned short* Gbt   = Cproj + (size_t)BT * EPROJ;         // [2048][2048] bf16
  unsigned short* Gat   = Gbt + (size_t)D2_SZ * BT;           // [2048][2048] bf16
  unsigned short* Sbf   = Gat + (size_t)D2_SZ * BT;           // [2][16][128][128] bf16

  prep_kernel<<<BT + 12288, 256, 0, stream>>>(feat, Wq, Wtb, Wpb, Wta, Wpa,
                                              Wgb, Wga, Nbf, Wb);
  gemm_fused<<<dim3(256), 512, 0, stream>>>(Nbf, Wb, Cproj, Gbt, Gat);
  score_direct<<<dim3(B_SZ, 2, 2), 256, 0, stream>>>(Cproj, Sbf);
  pv_mfma<<<dim3(D2_SZ / 128, B_SZ), 256, 0, stream>>>(Nbf, Sbf, Gbt, Gat, out);
}